// Round 6
// baseline (419.504 us; speedup 1.0000x reference)
//
#include <hip/hip_runtime.h>
#include <math.h>

#define NPTS 65536
#define DIM 64
#define NCODE 1024

typedef float f32x2 __attribute__((ext_vector_type(2)));
typedef float f32x4 __attribute__((ext_vector_type(4)));
typedef short bf16x8 __attribute__((ext_vector_type(8)));
typedef unsigned short u16x4 __attribute__((ext_vector_type(4)));

// output layout (flat float32 concat, reference return order)
#define OFF_LOSS 0ull
#define OFF_Q    1ull
#define OFF_PERP 4194305ull
#define OFF_ENC  4194306ull
#define OFF_IDX  71303170ull

__device__ __forceinline__ unsigned short bf16hi(float f) {
    unsigned u = __float_as_uint(f);
    unsigned r = u + 0x7FFFu + ((u >> 16) & 1u);   // RNE truncate to bf16
    return (unsigned short)(r >> 16);
}
__device__ __forceinline__ float bf16tof(unsigned short h) {
    return __uint_as_float(((unsigned)h) << 16);
}

// 8 consecutive fp32 (16B-aligned) -> hi/lo bf16x8
__device__ __forceinline__ void cvt8(const float* p, bf16x8& hi, bf16x8& lo) {
    float4 a = *(const float4*)p;
    float4 b = *(const float4*)(p + 4);
    float v[8] = {a.x, a.y, a.z, a.w, b.x, b.y, b.z, b.w};
#pragma unroll
    for (int i = 0; i < 8; ++i) {
        unsigned short h = bf16hi(v[i]);
        hi[i] = (short)h;
        lo[i] = (short)bf16hi(v[i] - bf16tof(h));
    }
}

// ---------------- emb fp32 -> (hi,lo) bf16 split ----------------
__global__ __launch_bounds__(256) void vq_ecvt(const float* __restrict__ emb,
                                               unsigned short* __restrict__ ehi,
                                               unsigned short* __restrict__ elo) {
    int t = blockIdx.x * 256 + threadIdx.x;
    float4 v = ((const float4*)emb)[t];
    float vv[4] = {v.x, v.y, v.z, v.w};
    u16x4 hi, lo;
#pragma unroll
    for (int i = 0; i < 4; ++i) {
        unsigned short h = bf16hi(vv[i]);
        hi[i] = h;
        lo[i] = bf16hi(vv[i] - bf16tof(h));
    }
    *(u16x4*)(ehi + (size_t)t * 4) = hi;
    *(u16x4*)(elo + (size_t)t * 4) = lo;
}

// ---------------- e2[k] = sum_d emb[k][d]^2 ----------------
__global__ __launch_bounds__(256) void vq_e2(const float* __restrict__ emb,
                                             float* __restrict__ e2) {
    int k = blockIdx.x * 256 + threadIdx.x;
    if (k >= NCODE) return;
    const float4* e4 = (const float4*)(emb + (size_t)k * DIM);
    float s = 0.f;
#pragma unroll
    for (int i = 0; i < DIM / 4; ++i) {
        float4 v = e4[i];
        s += v.x * v.x + v.y * v.y + v.z * v.z + v.w * v.w;
    }
    e2[k] = s;
}

// ---------------- distance argmin via bf16-split MFMA (scan phase only) ----------------
// Block = 4 waves, 64 points. fp32 x tile in LDS; bf16 hi/lo A-frags built at
// register-load time, 2 pt-halves (VGPR=64 measured). Wave wv scans its 256
// codes; B rows straight from L2 (no concurrent stream -> stays resident).
// Packed-u64 (sortable dist, code) argmin = exact first-min tie-break.
__global__ __launch_bounds__(256, 4) void vq_dist(const float* __restrict__ in,
                                                  const unsigned short* __restrict__ ehi,
                                                  const unsigned short* __restrict__ elo,
                                                  const float* __restrict__ e2,
                                                  float* __restrict__ out,
                                                  int* __restrict__ idx_ws,
                                                  unsigned int* __restrict__ hist) {
    __shared__ __align__(16) float lds_x[64][68];
    __shared__ unsigned long long cand[4][64];

    const int tid  = threadIdx.x;
    const int lane = tid & 63;
    const int wv   = __builtin_amdgcn_readfirstlane(tid >> 6);

    const int P0 = blockIdx.x * 64;
    const int b  = P0 >> 12;
    const int h  = (P0 >> 6) & 63;
    const float* base = in + (size_t)b * (DIM * 4096) + h * 64;

    // prologue: 64x64 fp32 tile, coalesced load, transpose into LDS
    {
        int d  = tid >> 2;
        int wq = tid & 3;
        const float* rowp = base + (size_t)d * 4096 + wq * 16;
#pragma unroll
        for (int j = 0; j < 4; ++j) {
            float4 v = *(const float4*)(rowp + j * 4);
            int w0 = wq * 16 + j * 4;
            lds_x[w0 + 0][d] = v.x;
            lds_x[w0 + 1][d] = v.y;
            lds_x[w0 + 2][d] = v.z;
            lds_x[w0 + 3][d] = v.w;
        }
    }
    __syncthreads();

    const int m15 = lane & 15;
    const int g4  = lane >> 4;
    const int kb  = g4 * 8;
    const int c0w = wv * 256;

#pragma unroll 1
    for (int half = 0; half < 2; ++half) {
        bf16x8 Ahi[2][2], Alo[2][2];
#pragma unroll
        for (int pt = 0; pt < 2; ++pt) {
            int p = (half * 2 + pt) * 16 + m15;
            cvt8(&lds_x[p][kb],      Ahi[pt][0], Alo[pt][0]);
            cvt8(&lds_x[p][kb + 32], Ahi[pt][1], Alo[pt][1]);
        }
        float best[2][4];
        int   bestk[2][4];
#pragma unroll
        for (int pt = 0; pt < 2; ++pt)
#pragma unroll
            for (int r = 0; r < 4; ++r) { best[pt][r] = INFINITY; bestk[pt][r] = 0; }

        for (int ct = 0; ct < 16; ++ct) {
            const int code = c0w + ct * 16 + m15;
            const unsigned short* eh = ehi + (size_t)code * 64 + kb;
            const unsigned short* el = elo + (size_t)code * 64 + kb;
            bf16x8 Bhi0 = *(const bf16x8*)eh;
            bf16x8 Bhi1 = *(const bf16x8*)(eh + 32);
            bf16x8 Blo0 = *(const bf16x8*)el;
            bf16x8 Blo1 = *(const bf16x8*)(el + 32);
            float e2v = e2[code];

#pragma unroll
            for (int pt = 0; pt < 2; ++pt) {
                f32x4 acc = {0.f, 0.f, 0.f, 0.f};
                acc = __builtin_amdgcn_mfma_f32_16x16x32_bf16(Ahi[pt][0], Bhi0, acc, 0, 0, 0);
                acc = __builtin_amdgcn_mfma_f32_16x16x32_bf16(Ahi[pt][1], Bhi1, acc, 0, 0, 0);
                acc = __builtin_amdgcn_mfma_f32_16x16x32_bf16(Ahi[pt][0], Blo0, acc, 0, 0, 0);
                acc = __builtin_amdgcn_mfma_f32_16x16x32_bf16(Ahi[pt][1], Blo1, acc, 0, 0, 0);
                acc = __builtin_amdgcn_mfma_f32_16x16x32_bf16(Alo[pt][0], Bhi0, acc, 0, 0, 0);
                acc = __builtin_amdgcn_mfma_f32_16x16x32_bf16(Alo[pt][1], Bhi1, acc, 0, 0, 0);
#pragma unroll
                for (int r = 0; r < 4; ++r) {
                    float dist = fmaf(-2.0f, acc[r], e2v);
                    if (dist < best[pt][r]) { best[pt][r] = dist; bestk[pt][r] = code; }
                }
            }
        }

#pragma unroll
        for (int pt = 0; pt < 2; ++pt) {
#pragma unroll
            for (int r = 0; r < 4; ++r) {
                unsigned u = __float_as_uint(best[pt][r]);
                u = (u & 0x80000000u) ? ~u : (u | 0x80000000u);
                unsigned long long key = ((unsigned long long)u << 32) | (unsigned)bestk[pt][r];
#pragma unroll
                for (int sm = 1; sm < 16; sm <<= 1) {
                    unsigned long long o = __shfl_xor(key, sm, 16);
                    key = (o < key) ? o : key;
                }
                if (m15 == 0) cand[wv][(half * 2 + pt) * 16 + g4 * 4 + r] = key;
            }
        }
    }
    __syncthreads();

    if (tid < 64) {
        unsigned long long k0 = cand[0][tid];
#pragma unroll
        for (int s = 1; s < 4; ++s) {
            unsigned long long o = cand[s][tid];
            if (o < k0) k0 = o;
        }
        int idx = (int)(k0 & 0xFFFFFFFFull);
        idx_ws[P0 + tid] = idx;
        out[OFF_IDX + P0 + tid] = (float)idx;
        atomicAdd(&hist[idx], 1u);
    }
}

// ---------------- q_ste + loss (plain stores, strided planes) ----------------
__global__ __launch_bounds__(256) void vq_q(const float* __restrict__ in,
                                            const float* __restrict__ emb,
                                            const int* __restrict__ idx_ws,
                                            float* __restrict__ out,
                                            float* __restrict__ loss_acc) {
    __shared__ int s_idx[64];
    const int tid = threadIdx.x;
    const int P0  = blockIdx.x * 64;
    if (tid < 64) s_idx[tid] = idx_ws[P0 + tid];
    __syncthreads();

    const int b  = P0 >> 12;
    const int h  = (P0 >> 6) & 63;
    const int w  = tid & 63;
    const int dg = tid >> 6;
    const int myidx = s_idx[w];
    const float* eq = emb + (size_t)myidx * DIM + dg * 16;
    const float* xb = in + ((size_t)b * 64 + dg * 16) * 4096 + h * 64 + w;
    float* qb = out + OFF_Q + ((size_t)b * 64 + dg * 16) * 4096 + h * 64 + w;

    float lsum = 0.f;
#pragma unroll
    for (int dd = 0; dd < 16; ++dd) {
        float x = xb[(size_t)dd * 4096];
        float diff = eq[dd] - x;
        lsum = fmaf(diff, diff, lsum);
        qb[(size_t)dd * 4096] = x + diff;          // exact STE form as reference
    }
    for (int off = 32; off > 0; off >>= 1) lsum += __shfl_down(lsum, off, 64);
    if ((tid & 63) == 0) atomicAdd(loss_acc, lsum);
}

// ---------------- one-hot: pure write stream, wave-per-row ----------------
// Wave handles 4 rows; per row each lane writes 4 f32x4 (wave instruction =
// 1024B contiguous). Row index is wave-uniform -> scalar load.
__global__ __launch_bounds__(256) void vq_onehot(const int* __restrict__ idx_ws,
                                                 float* __restrict__ out) {
    const int tid  = threadIdx.x;
    const int lane = tid & 63;
    const int wv   = tid >> 6;
    const int r0   = blockIdx.x * 16 + wv * 4;
    f32x4* enc4 = (f32x4*)(out + OFF_ENC);
#pragma unroll
    for (int rr = 0; rr < 4; ++rr) {
        const int row = r0 + rr;                   // wave-uniform
        const int target = idx_ws[row];
#pragma unroll
        for (int k = 0; k < 4; ++k) {
            const int j = k * 64 + lane;           // f32x4 index in row
            const int c0 = j * 4;
            f32x4 v;
            v.x = (c0 + 0 == target) ? 1.0f : 0.0f;
            v.y = (c0 + 1 == target) ? 1.0f : 0.0f;
            v.z = (c0 + 2 == target) ? 1.0f : 0.0f;
            v.w = (c0 + 3 == target) ? 1.0f : 0.0f;
            __builtin_nontemporal_store(v, &enc4[(size_t)row * 256 + j]);
        }
    }
}

// ---------------- finalize: loss scalar + perplexity ----------------
__global__ __launch_bounds__(1024) void vq_finalize(const unsigned int* __restrict__ hist,
                                                    const float* __restrict__ loss_acc,
                                                    float* __restrict__ out) {
    int t = threadIdx.x;
    float c = (float)hist[t];
    float pv = c * (1.0f / (float)NPTS);
    float term = pv * logf(pv + 1e-10f);

    __shared__ float red[16];
    float s = term;
    for (int off = 32; off > 0; off >>= 1) s += __shfl_down(s, off, 64);
    if ((t & 63) == 0) red[t >> 6] = s;
    __syncthreads();
    if (t < 16) {
        float v = red[t];
        for (int off = 8; off > 0; off >>= 1) v += __shfl_down(v, off, 64);
        if (t == 0) {
            out[OFF_PERP] = expf(-v);
            out[OFF_LOSS] = 0.25f * loss_acc[0] * (1.0f / 4194304.0f);
        }
    }
}

extern "C" void kernel_launch(void* const* d_in, const int* in_sizes, int n_in,
                              void* d_out, int out_size, void* d_ws, size_t ws_size,
                              hipStream_t stream) {
    const float* in  = (const float*)d_in[0];   // (16,64,64,64) BCHW
    const float* emb = (const float*)d_in[1];   // (1024,64)
    float* out = (float*)d_out;

    // ws layout: [0..15] loss_acc f32 | [16..1039] hist u32 | [1040..2063] e2 f32
    //            | idx i32[65536] | ehi ushort[65536] | elo ushort[65536]
    float* ws_f = (float*)d_ws;
    float* loss_acc = ws_f;
    unsigned int* hist = (unsigned int*)d_ws + 16;
    float* e2 = ws_f + 16 + NCODE;
    int* idx_ws = (int*)d_ws + 16 + 2 * NCODE;
    unsigned short* ehi = (unsigned short*)(ws_f + 16 + 2 * NCODE + NPTS);
    unsigned short* elo = ehi + (size_t)NCODE * DIM;

    (void)hipMemsetAsync(d_ws, 0, (16 + NCODE) * sizeof(float), stream);

    vq_ecvt<<<(NCODE * DIM / 4) / 256, 256, 0, stream>>>(emb, ehi, elo);
    vq_e2<<<NCODE / 256, 256, 0, stream>>>(emb, e2);
    vq_dist<<<NPTS / 64, 256, 0, stream>>>(in, ehi, elo, e2, out, idx_ws, hist);
    vq_q<<<NPTS / 64, 256, 0, stream>>>(in, emb, idx_ws, out, loss_acc);
    vq_onehot<<<NPTS / 16, 256, 0, stream>>>(idx_ws, out);
    vq_finalize<<<1, 1024, 0, stream>>>(hist, loss_acc, out);
}

// Round 7
// 184.750 us; speedup vs baseline: 2.2707x; 2.2707x over previous
//
#include <hip/hip_runtime.h>
#include <math.h>

#define NPTS 65536
#define DIM 64
#define NCODE 1024

typedef float f32x2 __attribute__((ext_vector_type(2)));
typedef float f32x4 __attribute__((ext_vector_type(4)));
typedef short bf16x8 __attribute__((ext_vector_type(8)));

// output layout (flat float32 concat, reference return order)
#define OFF_LOSS 0ull
#define OFF_Q    1ull
#define OFF_PERP 4194305ull
#define OFF_ENC  4194306ull
#define OFF_IDX  71303170ull

__device__ __forceinline__ unsigned short bf16hi(float f) {
    unsigned u = __float_as_uint(f);
    unsigned r = u + 0x7FFFu + ((u >> 16) & 1u);   // RNE truncate to bf16
    return (unsigned short)(r >> 16);
}
__device__ __forceinline__ float bf16tof(unsigned short h) {
    return __uint_as_float(((unsigned)h) << 16);
}

// 8 consecutive fp32 (16B-aligned) -> hi/lo bf16x8
__device__ __forceinline__ void cvt8(const float* p, bf16x8& hi, bf16x8& lo) {
    float4 a = *(const float4*)p;
    float4 b = *(const float4*)(p + 4);
    float v[8] = {a.x, a.y, a.z, a.w, b.x, b.y, b.z, b.w};
#pragma unroll
    for (int i = 0; i < 8; ++i) {
        unsigned short h = bf16hi(v[i]);
        hi[i] = (short)h;
        lo[i] = (short)bf16hi(v[i] - bf16tof(h));
    }
}
__device__ __forceinline__ void cvt8v(float4 a, float4 b, bf16x8& hi, bf16x8& lo) {
    float v[8] = {a.x, a.y, a.z, a.w, b.x, b.y, b.z, b.w};
#pragma unroll
    for (int i = 0; i < 8; ++i) {
        unsigned short h = bf16hi(v[i]);
        hi[i] = (short)h;
        lo[i] = (short)bf16hi(v[i] - bf16tof(h));
    }
}

// ---------------- distance argmin via bf16-split MFMA (scan phase only) ----------------
// Block = 4 waves, 64 points. fp32 x tile in LDS; A-frags (all 4 pt-tiles)
// built once via register cvt. Wave wv scans codes [256wv,256wv+256).
// B is loaded fp32 straight from emb (d_in -> L2-resident; ws bulk reads
// proved uncached, 436MB HBM fetch in r5/r6) and split in registers; ||e||^2
// computed inline from the same registers (shfl_xor over the 4 k-slices).
// dist = e2 - 2*(xh.eh + xh.el + xl.eh). Packed-u64 (sortable dist, code)
// argmin = exact first-min tie-break.
__global__ __launch_bounds__(256, 3) void vq_dist(const float* __restrict__ in,
                                                  const float* __restrict__ emb,
                                                  float* __restrict__ out,
                                                  int* __restrict__ idx_ws,
                                                  unsigned int* __restrict__ hist) {
    __shared__ __align__(16) float lds_x[64][68];
    __shared__ unsigned long long cand[4][64];

    const int tid  = threadIdx.x;
    const int lane = tid & 63;
    const int wv   = __builtin_amdgcn_readfirstlane(tid >> 6);

    const int P0 = blockIdx.x * 64;
    const int b  = P0 >> 12;
    const int h  = (P0 >> 6) & 63;
    const float* base = in + (size_t)b * (DIM * 4096) + h * 64;

    // prologue: 64x64 fp32 tile, coalesced load, transpose into LDS
    {
        int d  = tid >> 2;
        int wq = tid & 3;
        const float* rowp = base + (size_t)d * 4096 + wq * 16;
#pragma unroll
        for (int j = 0; j < 4; ++j) {
            float4 v = *(const float4*)(rowp + j * 4);
            int w0 = wq * 16 + j * 4;
            lds_x[w0 + 0][d] = v.x;
            lds_x[w0 + 1][d] = v.y;
            lds_x[w0 + 2][d] = v.z;
            lds_x[w0 + 3][d] = v.w;
        }
    }
    __syncthreads();

    const int m15 = lane & 15;
    const int g4  = lane >> 4;
    const int kb  = g4 * 8;            // this lane's k-slice base (8 fp32)
    const int c0w = wv * 256;          // this wave's code slice (ascending)

    // A fragments, all 4 point-tiles resident (A row = lane&15, k = kb..)
    bf16x8 Ahi[4][2], Alo[4][2];
#pragma unroll
    for (int pt = 0; pt < 4; ++pt) {
        int p = pt * 16 + m15;
        cvt8(&lds_x[p][kb],      Ahi[pt][0], Alo[pt][0]);
        cvt8(&lds_x[p][kb + 32], Ahi[pt][1], Alo[pt][1]);
    }

    float best[4][4];
    int   bestk[4][4];
#pragma unroll
    for (int pt = 0; pt < 4; ++pt)
#pragma unroll
        for (int r = 0; r < 4; ++r) { best[pt][r] = INFINITY; bestk[pt][r] = 0; }

    for (int ct = 0; ct < 16; ++ct) {
        const int code = c0w + ct * 16 + m15;          // B col = lane&15
        const float* ep = emb + (size_t)code * DIM + kb;
        float4 e0 = *(const float4*)ep;
        float4 e1 = *(const float4*)(ep + 4);
        float4 e2a = *(const float4*)(ep + 32);
        float4 e3 = *(const float4*)(ep + 36);

        // ||e||^2: 16 local squares, then sum the 4 k-slices (xor keeps m15)
        float sq = e0.x * e0.x;
        sq = fmaf(e0.y, e0.y, sq); sq = fmaf(e0.z, e0.z, sq); sq = fmaf(e0.w, e0.w, sq);
        sq = fmaf(e1.x, e1.x, sq); sq = fmaf(e1.y, e1.y, sq); sq = fmaf(e1.z, e1.z, sq); sq = fmaf(e1.w, e1.w, sq);
        sq = fmaf(e2a.x, e2a.x, sq); sq = fmaf(e2a.y, e2a.y, sq); sq = fmaf(e2a.z, e2a.z, sq); sq = fmaf(e2a.w, e2a.w, sq);
        sq = fmaf(e3.x, e3.x, sq); sq = fmaf(e3.y, e3.y, sq); sq = fmaf(e3.z, e3.z, sq); sq = fmaf(e3.w, e3.w, sq);
        sq += __shfl_xor(sq, 16, 64);
        sq += __shfl_xor(sq, 32, 64);
        const float e2v = sq;

        bf16x8 Bhi0, Blo0, Bhi1, Blo1;
        cvt8v(e0, e1, Bhi0, Blo0);
        cvt8v(e2a, e3, Bhi1, Blo1);

#pragma unroll
        for (int pt = 0; pt < 4; ++pt) {
            f32x4 acc = {0.f, 0.f, 0.f, 0.f};
            acc = __builtin_amdgcn_mfma_f32_16x16x32_bf16(Ahi[pt][0], Bhi0, acc, 0, 0, 0);
            acc = __builtin_amdgcn_mfma_f32_16x16x32_bf16(Ahi[pt][1], Bhi1, acc, 0, 0, 0);
            acc = __builtin_amdgcn_mfma_f32_16x16x32_bf16(Ahi[pt][0], Blo0, acc, 0, 0, 0);
            acc = __builtin_amdgcn_mfma_f32_16x16x32_bf16(Ahi[pt][1], Blo1, acc, 0, 0, 0);
            acc = __builtin_amdgcn_mfma_f32_16x16x32_bf16(Alo[pt][0], Bhi0, acc, 0, 0, 0);
            acc = __builtin_amdgcn_mfma_f32_16x16x32_bf16(Alo[pt][1], Bhi1, acc, 0, 0, 0);
#pragma unroll
            for (int r = 0; r < 4; ++r) {
                float dist = fmaf(-2.0f, acc[r], e2v);
                if (dist < best[pt][r]) { best[pt][r] = dist; bestk[pt][r] = code; }
            }
        }
    }

    // per-wave cross-lane argmin over 16 cols, lexicographic (dist, code)
#pragma unroll
    for (int pt = 0; pt < 4; ++pt) {
#pragma unroll
        for (int r = 0; r < 4; ++r) {
            unsigned u = __float_as_uint(best[pt][r]);
            u = (u & 0x80000000u) ? ~u : (u | 0x80000000u);   // monotone f32->u32
            unsigned long long key = ((unsigned long long)u << 32) | (unsigned)bestk[pt][r];
#pragma unroll
            for (int sm = 1; sm < 16; sm <<= 1) {
                unsigned long long o = __shfl_xor(key, sm, 16);
                key = (o < key) ? o : key;
            }
            if (m15 == 0) cand[wv][pt * 16 + g4 * 4 + r] = key;
        }
    }
    __syncthreads();

    if (tid < 64) {   // merge 4 wave-slices (ascending -> first-min tie-break)
        unsigned long long k0 = cand[0][tid];
#pragma unroll
        for (int s = 1; s < 4; ++s) {
            unsigned long long o = cand[s][tid];
            if (o < k0) k0 = o;
        }
        int idx = (int)(k0 & 0xFFFFFFFFull);
        idx_ws[P0 + tid] = idx;
        out[OFF_IDX + P0 + tid] = (float)idx;
        atomicAdd(&hist[idx], 1u);
    }
}

// ---------------- q_ste + loss (plain stores, strided planes) ----------------
__global__ __launch_bounds__(256) void vq_q(const float* __restrict__ in,
                                            const float* __restrict__ emb,
                                            const int* __restrict__ idx_ws,
                                            float* __restrict__ out,
                                            float* __restrict__ loss_acc) {
    __shared__ int s_idx[64];
    const int tid = threadIdx.x;
    const int P0  = blockIdx.x * 64;
    if (tid < 64) s_idx[tid] = idx_ws[P0 + tid];
    __syncthreads();

    const int b  = P0 >> 12;
    const int h  = (P0 >> 6) & 63;
    const int w  = tid & 63;
    const int dg = tid >> 6;
    const int myidx = s_idx[w];
    const float* eq = emb + (size_t)myidx * DIM + dg * 16;
    const float* xb = in + ((size_t)b * 64 + dg * 16) * 4096 + h * 64 + w;
    float* qb = out + OFF_Q + ((size_t)b * 64 + dg * 16) * 4096 + h * 64 + w;

    float lsum = 0.f;
#pragma unroll
    for (int dd = 0; dd < 16; ++dd) {
        float x = xb[(size_t)dd * 4096];
        float diff = eq[dd] - x;
        lsum = fmaf(diff, diff, lsum);
        qb[(size_t)dd * 4096] = x + diff;          // exact STE form as reference
    }
    for (int off = 32; off > 0; off >>= 1) lsum += __shfl_down(lsum, off, 64);
    if ((tid & 63) == 0) atomicAdd(loss_acc, lsum);
}

// ---------------- one-hot: pure write stream, wave-per-row ----------------
__global__ __launch_bounds__(256) void vq_onehot(const int* __restrict__ idx_ws,
                                                 float* __restrict__ out) {
    const int tid  = threadIdx.x;
    const int lane = tid & 63;
    const int wv   = tid >> 6;
    const int r0   = blockIdx.x * 16 + wv * 4;
    f32x4* enc4 = (f32x4*)(out + OFF_ENC);
#pragma unroll
    for (int rr = 0; rr < 4; ++rr) {
        const int row = r0 + rr;                   // wave-uniform
        const int target = idx_ws[row];
#pragma unroll
        for (int k = 0; k < 4; ++k) {
            const int j = k * 64 + lane;           // f32x4 index in row
            const int c0 = j * 4;
            f32x4 v;
            v.x = (c0 + 0 == target) ? 1.0f : 0.0f;
            v.y = (c0 + 1 == target) ? 1.0f : 0.0f;
            v.z = (c0 + 2 == target) ? 1.0f : 0.0f;
            v.w = (c0 + 3 == target) ? 1.0f : 0.0f;
            __builtin_nontemporal_store(v, &enc4[(size_t)row * 256 + j]);
        }
    }
}

// ---------------- finalize: loss scalar + perplexity ----------------
__global__ __launch_bounds__(1024) void vq_finalize(const unsigned int* __restrict__ hist,
                                                    const float* __restrict__ loss_acc,
                                                    float* __restrict__ out) {
    int t = threadIdx.x;
    float c = (float)hist[t];
    float pv = c * (1.0f / (float)NPTS);
    float term = pv * logf(pv + 1e-10f);

    __shared__ float red[16];
    float s = term;
    for (int off = 32; off > 0; off >>= 1) s += __shfl_down(s, off, 64);
    if ((t & 63) == 0) red[t >> 6] = s;
    __syncthreads();
    if (t < 16) {
        float v = red[t];
        for (int off = 8; off > 0; off >>= 1) v += __shfl_down(v, off, 64);
        if (t == 0) {
            out[OFF_PERP] = expf(-v);
            out[OFF_LOSS] = 0.25f * loss_acc[0] * (1.0f / 4194304.0f);
        }
    }
}

extern "C" void kernel_launch(void* const* d_in, const int* in_sizes, int n_in,
                              void* d_out, int out_size, void* d_ws, size_t ws_size,
                              hipStream_t stream) {
    const float* in  = (const float*)d_in[0];   // (16,64,64,64) BCHW
    const float* emb = (const float*)d_in[1];   // (1024,64)
    float* out = (float*)d_out;

    // ws layout: [0..15] loss_acc f32 | [16..1039] hist u32 | idx i32[65536]
    float* ws_f = (float*)d_ws;
    float* loss_acc = ws_f;
    unsigned int* hist = (unsigned int*)d_ws + 16;
    int* idx_ws = (int*)d_ws + 16 + NCODE;

    (void)hipMemsetAsync(d_ws, 0, (16 + NCODE) * sizeof(float), stream);

    vq_dist<<<NPTS / 64, 256, 0, stream>>>(in, emb, out, idx_ws, hist);
    vq_q<<<NPTS / 64, 256, 0, stream>>>(in, emb, idx_ws, out, loss_acc);
    vq_onehot<<<NPTS / 16, 256, 0, stream>>>(idx_ws, out);
    vq_finalize<<<1, 1024, 0, stream>>>(hist, loss_acc, out);
}

// Round 8
// 138.308 us; speedup vs baseline: 3.0331x; 1.3358x over previous
//
#include <hip/hip_runtime.h>
#include <math.h>

#define NPTS 65536
#define DIM 64
#define NCODE 1024

typedef float f32x2 __attribute__((ext_vector_type(2)));
typedef float f32x4 __attribute__((ext_vector_type(4)));
typedef short bf16x8 __attribute__((ext_vector_type(8)));

// output layout (flat float32 concat, reference return order)
#define OFF_LOSS 0ull
#define OFF_Q    1ull
#define OFF_PERP 4194305ull
#define OFF_ENC  4194306ull
#define OFF_IDX  71303170ull

__device__ __forceinline__ unsigned short bf16hi(float f) {
    unsigned u = __float_as_uint(f);
    unsigned r = u + 0x7FFFu + ((u >> 16) & 1u);   // RNE truncate to bf16
    return (unsigned short)(r >> 16);
}
__device__ __forceinline__ float bf16tof(unsigned short h) {
    return __uint_as_float(((unsigned)h) << 16);
}

// 8 consecutive fp32 (16B-aligned) -> hi/lo bf16x8
__device__ __forceinline__ void cvt8(const float* p, bf16x8& hi, bf16x8& lo) {
    float4 a = *(const float4*)p;
    float4 b = *(const float4*)(p + 4);
    float v[8] = {a.x, a.y, a.z, a.w, b.x, b.y, b.z, b.w};
#pragma unroll
    for (int i = 0; i < 8; ++i) {
        unsigned short h = bf16hi(v[i]);
        hi[i] = (short)h;
        lo[i] = (short)bf16hi(v[i] - bf16tof(h));
    }
}
__device__ __forceinline__ void cvt8v(float4 a, float4 b, bf16x8& hi, bf16x8& lo) {
    float v[8] = {a.x, a.y, a.z, a.w, b.x, b.y, b.z, b.w};
#pragma unroll
    for (int i = 0; i < 8; ++i) {
        unsigned short h = bf16hi(v[i]);
        hi[i] = (short)h;
        lo[i] = (short)bf16hi(v[i] - bf16tof(h));
    }
}

// ---------------- distance argmin via bf16-split MFMA (scan phase only) ----------------
// Block = 4 waves, 64 points. fp32 x tile in LDS; A-frags (all 4 pt-tiles)
// built once via register cvt. Wave wv scans codes [256wv,256wv+256).
// B loaded fp32 from emb (d_in -> L2 caches it; d_ws bulk reads are uncached,
// r5/r6 evidence). ||e||^2 inline via shfl_xor over the 4 k-slices.
// dist = e2 - 2*(xh.eh + xh.el + xl.eh). Packed-u64 argmin = exact
// first-min tie-break. Indices land ONLY in out[OFF_IDX] (cached d_out).
__global__ __launch_bounds__(256, 3) void vq_dist(const float* __restrict__ in,
                                                  const float* __restrict__ emb,
                                                  float* __restrict__ out,
                                                  unsigned int* __restrict__ hist) {
    __shared__ __align__(16) float lds_x[64][68];
    __shared__ unsigned long long cand[4][64];

    const int tid  = threadIdx.x;
    const int lane = tid & 63;
    const int wv   = __builtin_amdgcn_readfirstlane(tid >> 6);

    const int P0 = blockIdx.x * 64;
    const int b  = P0 >> 12;
    const int h  = (P0 >> 6) & 63;
    const float* base = in + (size_t)b * (DIM * 4096) + h * 64;

    // prologue: 64x64 fp32 tile, coalesced load, transpose into LDS
    {
        int d  = tid >> 2;
        int wq = tid & 3;
        const float* rowp = base + (size_t)d * 4096 + wq * 16;
#pragma unroll
        for (int j = 0; j < 4; ++j) {
            float4 v = *(const float4*)(rowp + j * 4);
            int w0 = wq * 16 + j * 4;
            lds_x[w0 + 0][d] = v.x;
            lds_x[w0 + 1][d] = v.y;
            lds_x[w0 + 2][d] = v.z;
            lds_x[w0 + 3][d] = v.w;
        }
    }
    __syncthreads();

    const int m15 = lane & 15;
    const int g4  = lane >> 4;
    const int kb  = g4 * 8;            // this lane's k-slice base (8 fp32)
    const int c0w = wv * 256;          // this wave's code slice (ascending)

    // A fragments, all 4 point-tiles resident (A row = lane&15, k = kb..)
    bf16x8 Ahi[4][2], Alo[4][2];
#pragma unroll
    for (int pt = 0; pt < 4; ++pt) {
        int p = pt * 16 + m15;
        cvt8(&lds_x[p][kb],      Ahi[pt][0], Alo[pt][0]);
        cvt8(&lds_x[p][kb + 32], Ahi[pt][1], Alo[pt][1]);
    }

    float best[4][4];
    int   bestk[4][4];
#pragma unroll
    for (int pt = 0; pt < 4; ++pt)
#pragma unroll
        for (int r = 0; r < 4; ++r) { best[pt][r] = INFINITY; bestk[pt][r] = 0; }

    for (int ct = 0; ct < 16; ++ct) {
        const int code = c0w + ct * 16 + m15;          // B col = lane&15
        const float* ep = emb + (size_t)code * DIM + kb;
        float4 e0 = *(const float4*)ep;
        float4 e1 = *(const float4*)(ep + 4);
        float4 e2a = *(const float4*)(ep + 32);
        float4 e3 = *(const float4*)(ep + 36);

        // ||e||^2: 16 local squares, then sum the 4 k-slices (xor keeps m15)
        float sq = e0.x * e0.x;
        sq = fmaf(e0.y, e0.y, sq); sq = fmaf(e0.z, e0.z, sq); sq = fmaf(e0.w, e0.w, sq);
        sq = fmaf(e1.x, e1.x, sq); sq = fmaf(e1.y, e1.y, sq); sq = fmaf(e1.z, e1.z, sq); sq = fmaf(e1.w, e1.w, sq);
        sq = fmaf(e2a.x, e2a.x, sq); sq = fmaf(e2a.y, e2a.y, sq); sq = fmaf(e2a.z, e2a.z, sq); sq = fmaf(e2a.w, e2a.w, sq);
        sq = fmaf(e3.x, e3.x, sq); sq = fmaf(e3.y, e3.y, sq); sq = fmaf(e3.z, e3.z, sq); sq = fmaf(e3.w, e3.w, sq);
        sq += __shfl_xor(sq, 16, 64);
        sq += __shfl_xor(sq, 32, 64);
        const float e2v = sq;

        bf16x8 Bhi0, Blo0, Bhi1, Blo1;
        cvt8v(e0, e1, Bhi0, Blo0);
        cvt8v(e2a, e3, Bhi1, Blo1);

#pragma unroll
        for (int pt = 0; pt < 4; ++pt) {
            f32x4 acc = {0.f, 0.f, 0.f, 0.f};
            acc = __builtin_amdgcn_mfma_f32_16x16x32_bf16(Ahi[pt][0], Bhi0, acc, 0, 0, 0);
            acc = __builtin_amdgcn_mfma_f32_16x16x32_bf16(Ahi[pt][1], Bhi1, acc, 0, 0, 0);
            acc = __builtin_amdgcn_mfma_f32_16x16x32_bf16(Ahi[pt][0], Blo0, acc, 0, 0, 0);
            acc = __builtin_amdgcn_mfma_f32_16x16x32_bf16(Ahi[pt][1], Blo1, acc, 0, 0, 0);
            acc = __builtin_amdgcn_mfma_f32_16x16x32_bf16(Alo[pt][0], Bhi0, acc, 0, 0, 0);
            acc = __builtin_amdgcn_mfma_f32_16x16x32_bf16(Alo[pt][1], Bhi1, acc, 0, 0, 0);
#pragma unroll
            for (int r = 0; r < 4; ++r) {
                float dist = fmaf(-2.0f, acc[r], e2v);
                if (dist < best[pt][r]) { best[pt][r] = dist; bestk[pt][r] = code; }
            }
        }
    }

    // per-wave cross-lane argmin over 16 cols, lexicographic (dist, code)
#pragma unroll
    for (int pt = 0; pt < 4; ++pt) {
#pragma unroll
        for (int r = 0; r < 4; ++r) {
            unsigned u = __float_as_uint(best[pt][r]);
            u = (u & 0x80000000u) ? ~u : (u | 0x80000000u);   // monotone f32->u32
            unsigned long long key = ((unsigned long long)u << 32) | (unsigned)bestk[pt][r];
#pragma unroll
            for (int sm = 1; sm < 16; sm <<= 1) {
                unsigned long long o = __shfl_xor(key, sm, 16);
                key = (o < key) ? o : key;
            }
            if (m15 == 0) cand[wv][pt * 16 + g4 * 4 + r] = key;
        }
    }
    __syncthreads();

    if (tid < 64) {   // merge 4 wave-slices (ascending -> first-min tie-break)
        unsigned long long k0 = cand[0][tid];
#pragma unroll
        for (int s = 1; s < 4; ++s) {
            unsigned long long o = cand[s][tid];
            if (o < k0) k0 = o;
        }
        int idx = (int)(k0 & 0xFFFFFFFFull);
        out[OFF_IDX + P0 + tid] = (float)idx;      // sole idx sink (cached d_out)
        atomicAdd(&hist[idx], 1u);
    }
}

// ---------------- stream: q_ste + loss + one-hot (idx read from d_out) ----------------
__global__ __launch_bounds__(256) void vq_stream(const float* __restrict__ in,
                                                 const float* __restrict__ emb,
                                                 float* __restrict__ out,
                                                 float* __restrict__ loss_acc) {
    __shared__ int s_idx[64];
    const int tid = threadIdx.x;
    const int P0  = blockIdx.x * 64;
    if (tid < 64) s_idx[tid] = (int)out[OFF_IDX + P0 + tid];   // exact for 0..1023
    __syncthreads();

    const int b  = P0 >> 12;
    const int h  = (P0 >> 6) & 63;
    const int w  = tid & 63;
    const int dg = tid >> 6;                       // wave id = d-group
    {
        const int myidx = s_idx[w];
        const float* eq = emb + (size_t)myidx * DIM + dg * 16;
        const float* xb = in + ((size_t)b * 64 + dg * 16) * 4096 + h * 64 + w;
        float* qb = out + OFF_Q + ((size_t)b * 64 + dg * 16) * 4096 + h * 64 + w;

        float lsum = 0.f;
#pragma unroll
        for (int dd = 0; dd < 16; ++dd) {
            float x = xb[(size_t)dd * 4096];
            float diff = eq[dd] - x;
            lsum = fmaf(diff, diff, lsum);
            qb[(size_t)dd * 4096] = x + diff;      // exact STE form; plain store
        }
        for (int off = 32; off > 0; off >>= 1) lsum += __shfl_down(lsum, off, 64);
        if ((tid & 63) == 0) atomicAdd(loss_acc, lsum);
    }

    // one-hot: wave wv owns rows [16wv, 16wv+16); per row each lane stores
    // one f32x4 x4 -> 1024B/wave-instruction, nontemporal (no L2 pollution).
    {
        const int wv = tid >> 6;
        const int lane = tid & 63;
        f32x4* enc4 = (f32x4*)(out + OFF_ENC + (unsigned long long)P0 * NCODE);
#pragma unroll
        for (int rr = 0; rr < 16; ++rr) {
            const int row = wv * 16 + rr;          // wave-uniform
            const int target = s_idx[row];
#pragma unroll
            for (int k = 0; k < 4; ++k) {
                const int j = k * 64 + lane;       // f32x4 index in row
                const int c0 = j * 4;
                f32x4 v;
                v.x = (c0 + 0 == target) ? 1.0f : 0.0f;
                v.y = (c0 + 1 == target) ? 1.0f : 0.0f;
                v.z = (c0 + 2 == target) ? 1.0f : 0.0f;
                v.w = (c0 + 3 == target) ? 1.0f : 0.0f;
                __builtin_nontemporal_store(v, &enc4[(size_t)row * 256 + j]);
            }
        }
    }
}

// ---------------- finalize: loss scalar + perplexity ----------------
__global__ __launch_bounds__(1024) void vq_finalize(const unsigned int* __restrict__ hist,
                                                    const float* __restrict__ loss_acc,
                                                    float* __restrict__ out) {
    int t = threadIdx.x;
    float c = (float)hist[t];
    float pv = c * (1.0f / (float)NPTS);
    float term = pv * logf(pv + 1e-10f);

    __shared__ float red[16];
    float s = term;
    for (int off = 32; off > 0; off >>= 1) s += __shfl_down(s, off, 64);
    if ((t & 63) == 0) red[t >> 6] = s;
    __syncthreads();
    if (t < 16) {
        float v = red[t];
        for (int off = 8; off > 0; off >>= 1) v += __shfl_down(v, off, 64);
        if (t == 0) {
            out[OFF_PERP] = expf(-v);
            out[OFF_LOSS] = 0.25f * loss_acc[0] * (1.0f / 4194304.0f);
        }
    }
}

extern "C" void kernel_launch(void* const* d_in, const int* in_sizes, int n_in,
                              void* d_out, int out_size, void* d_ws, size_t ws_size,
                              hipStream_t stream) {
    const float* in  = (const float*)d_in[0];   // (16,64,64,64) BCHW
    const float* emb = (const float*)d_in[1];   // (1024,64)
    float* out = (float*)d_out;

    // ws: [0..15] loss_acc f32 | [16..1039] hist u32  (atomics only; no bulk)
    float* ws_f = (float*)d_ws;
    float* loss_acc = ws_f;
    unsigned int* hist = (unsigned int*)d_ws + 16;

    (void)hipMemsetAsync(d_ws, 0, (16 + NCODE) * sizeof(float), stream);

    vq_dist<<<NPTS / 64, 256, 0, stream>>>(in, emb, out, hist);
    vq_stream<<<NPTS / 64, 256, 0, stream>>>(in, emb, out, loss_acc);
    vq_finalize<<<1, 1024, 0, stream>>>(hist, loss_acc, out);
}